// Round 17
// baseline (119.682 us; speedup 1.0000x reference)
//
#include <hip/hip_runtime.h>

#define HPIX 256
#define WPIX 256
#define TSX 16
#define TSY 16
#define NTILE 256            // 16x16 tiles of 16x16 px
#define FCH 256
#define SEG_FLAT 16          // segments over all faces (fallback path)
#define RSEG 16              // waves (bin segments) per quadrant block
#define CAP 6144             // LDS sort capacity (entries per tile bin)
#define NB2 1024             // per-tile depth-lb buckets
#define SENTU 0xFFFFFFFFu
#define BIGF 1000000000.0f
#define EPSF 1e-8f
#define MARGIN 0.125f
#define HP_SLOP 0.0625f      // >= 4x the FP eval error bound (~0.015 w-units)
#define EPSB 1e-3f           // break slop >> lb FP error (<1e-4)
#define WBOUND 64.0f         // corner-|w| bound for tight corner-lb FP error
#define INIT_PACK 0xFFFFFFFFFFFFFFFFull

struct FaceRec {
  float x2, y2, a0, b0, a1, b1, inv, z0, z1, z2;
  float xmin, ymin, xmax, ymax;
};

// Compute the per-face record with EXACTLY the reference's op order (no FMA).
__device__ __forceinline__ FaceRec make_rec(const float* __restrict__ vb,
                                            const int* __restrict__ faces, int f) {
#pragma clang fp contract(off)
  FaceRec r;
  int i0 = faces[f * 3 + 0], i1 = faces[f * 3 + 1], i2 = faces[f * 3 + 2];
  float x0 = vb[i0 * 3 + 0], y0 = vb[i0 * 3 + 1], z0 = vb[i0 * 3 + 2];
  float x1 = vb[i1 * 3 + 0], y1 = vb[i1 * 3 + 1], z1 = vb[i1 * 3 + 2];
  float x2 = vb[i2 * 3 + 0], y2 = vb[i2 * 3 + 1], z2 = vb[i2 * 3 + 2];
  float px0 = x0 / z0, py0 = y0 / z0;
  float px1 = x1 / z1, py1 = y1 / z1;
  float px2 = x2 / z2, py2 = y2 / z2;
  float a0 = py1 - py2, b0 = px2 - px1;   // (y1-y2), (x2-x1)
  float a1 = py2 - py0, b1 = px0 - px2;   // (y2-y0), (x0-x2)
  float dy02 = py0 - py2;
  float denom = a0 * b1 + b0 * dy02;      // (y1-y2)*(x0-x2) + (x2-x1)*(y0-y2)
  bool nz = fabsf(denom) > EPSF;
  bool valid = nz && (z0 > 0.0f) && (z1 > 0.0f) && (z2 > 0.0f);
  r.x2 = px2; r.y2 = py2; r.a0 = a0; r.b0 = b0; r.a1 = a1; r.b1 = b1;
  r.inv = valid ? 1.0f / denom : 0.0f;
  r.z0 = z0; r.z1 = z1;
  r.z2 = valid ? z2 : -1.0f;              // invalid -> depth<0 -> fails depth>0
  if (valid) {
    r.xmin = fminf(px0, fminf(px1, px2)) - MARGIN;
    r.xmax = fmaxf(px0, fmaxf(px1, px2)) + MARGIN;
    r.ymin = fminf(py0, fminf(py1, py2)) - MARGIN;
    r.ymax = fmaxf(py0, fmaxf(py1, py2)) + MARGIN;
  } else {
    r.xmin = 2.0f * BIGF; r.xmax = -2.0f * BIGF;
    r.ymin = 2.0f * BIGF; r.ymax = -2.0f * BIGF;
  }
  return r;
}

// prep (dual layout): 64B-aligned combined record (random access: one cache
// line covers A+B+Z+D) AND dense 16B bbox array (streaming sieve).
__global__ void prep_both(const float* __restrict__ verts,
                          const int* __restrict__ faces,
                          float4* __restrict__ recs, float4* __restrict__ dq,
                          int V, int F, int NIMG) {
  int idx = blockIdx.x * blockDim.x + threadIdx.x;
  if (idx >= NIMG * F) return;
  int n = idx / F, f = idx - n * F;
  FaceRec r = make_rec(verts + (size_t)n * V * 3, faces, f);
  float4* o = recs + (size_t)idx * 4;
  float4 D = make_float4(r.xmin, r.ymin, r.xmax, r.ymax);
  o[0] = make_float4(r.x2, r.y2, r.a0, r.b0);
  o[1] = make_float4(r.a1, r.b1, r.inv, r.z0);
  o[2] = make_float4(r.z1, r.z2, 0.0f, 0.0f);
  o[3] = D;
  dq[idx] = D;
}

// Per (tile,image), 512 threads: stream faces (dense bbox sieve via dq),
// keep = bbox overlap + conservative corner half-plane. Sort key:
// lb = max(corner-min depth, minz - margin). Barrier-free face loop
// (round-14: entry order irrelevant, counting sort reorders anyway).
__global__ __launch_bounds__(512) void bin_sort_kernel(
    const float4* __restrict__ recs_g, const float4* __restrict__ dq_g,
    unsigned int* __restrict__ cursors, unsigned int* __restrict__ bins,
    unsigned int* __restrict__ covmask, int F, int FP) {
#pragma clang fp contract(off)
  const int t = blockIdx.x, n = blockIdx.y;
  const int tlx = t & 15, tly = t >> 4;
  const float X0 = (float)(tlx * TSX), X1 = X0 + (float)(TSX - 1);
  const float Y0 = (float)(tly * TSY), Y1 = Y0 + (float)(TSY - 1);
  __shared__ unsigned int s_ent[CAP];
  __shared__ unsigned int s_hist[NB2];
  __shared__ unsigned int s_scan[256];
  __shared__ unsigned int s_cur;
  __shared__ unsigned long long s_wcov[8][4];
  const int tid = (int)threadIdx.x;
  const int lane = tid & 63, wid = tid >> 6;
  if (tid == 0) s_cur = 0u;
  for (int i = tid; i < NB2; i += 512) s_hist[i] = 0u;
  __syncthreads();
  const float4* rb = recs_g + (size_t)n * F * 4;
  const float4* dq = dq_g + (size_t)n * F;
  unsigned int* bin = bins + (size_t)(n * NTILE + t) * FP;
  unsigned long long cov[4] = {0ull, 0ull, 0ull, 0ull};
  for (int j = tid; j < F; j += 512) {
    bool keep = false;
    unsigned int e = 0u;
    {
      float4 D = dq[j];
      keep = (D.x <= X1) && (D.z >= X0) && (D.y <= Y1) && (D.w >= Y0);
      if (keep) {
        float4 A = rb[j * 4 + 0];
        float4 B = rb[j * 4 + 1];
        float4 Z = rb[j * 4 + 2];
        float inv = B.z;
        // minz lower bound: valid for any passing pixel (w>=0, sum=1+-2.4e-7
        // => depth >= minz - 1.2e-6; margin 2e-5 >> error).
        float minz3 = fminf(B.w, fminf(Z.x, Z.y));
        float lb = minz3 - (1e-5f + 1e-5f * fabsf(minz3));
        if (fabsf(inv) <= 1.0f) {
          float m0 = -3.0e38f, m1 = -3.0e38f, m2 = -3.0e38f;
          float g = 0.0f, dmin = 3.0e38f;
#pragma unroll
          for (int c = 0; c < 4; ++c) {
            float ccx = (c & 1) ? X1 : X0;
            float ccy = (c & 2) ? Y1 : Y0;
            float bx = ccx - A.x, by = ccy - A.y;
            float w0 = (A.z * bx + A.w * by) * inv;
            float w1 = (B.x * bx + B.y * by) * inv;
            float w2 = 1.0f - w0 - w1;
            float dc = (w0 * B.w + w1 * Z.x) + w2 * Z.y;
            m0 = fmaxf(m0, w0); m1 = fmaxf(m1, w1); m2 = fmaxf(m2, w2);
            g = fmaxf(g, fmaxf(fabsf(w0), fmaxf(fabsf(w1), fabsf(w2))));
            dmin = fminf(dmin, dc);
          }
          keep = (m0 >= -HP_SLOP) && (m1 >= -HP_SLOP) && (m2 >= -HP_SLOP);
          if (g <= WBOUND) lb = fmaxf(lb, dmin);   // tighter of the two bounds
        }
        if (keep) {
          int bq = (lb <= 1.0f) ? 0 : (int)floorf((lb - 1.0f) * (float)NB2);
          bq = bq < 0 ? 0 : (bq > NB2 - 1 ? NB2 - 1 : bq);
          e = ((unsigned int)bq << 16) | (unsigned int)j;
          atomicAdd(&s_hist[bq], 1u);
          // coverage rectangle into registers (no LDS atomics -- r9 lesson)
          int cmin = (int)ceilf(D.x - X0);  cmin = cmin < 0 ? 0 : cmin;
          int cmax = (int)floorf(D.z - X0); cmax = cmax > 15 ? 15 : cmax;
          int rmin = (int)ceilf(D.y - Y0);  rmin = rmin < 0 ? 0 : rmin;
          int rmax = (int)floorf(D.w - Y0); rmax = rmax > 15 ? 15 : rmax;
          if (cmin <= cmax && rmin <= rmax) {
            unsigned int colm = (0xFFFFu << cmin) & (0xFFFFu >> (15 - cmax));
            unsigned int rowm = (0xFFFFu << rmin) & (0xFFFFu >> (15 - rmax));
            unsigned long long rep =
                (unsigned long long)colm * 0x0001000100010001ull;
#pragma unroll
            for (int k = 0; k < 4; ++k) {
              unsigned int rm4 = (rowm >> (4 * k)) & 0xFu;
              unsigned long long mk =
                  ((rm4 & 1u) ? 0x000000000000FFFFull : 0ull) |
                  ((rm4 & 2u) ? 0x00000000FFFF0000ull : 0ull) |
                  ((rm4 & 4u) ? 0x0000FFFF00000000ull : 0ull) |
                  ((rm4 & 8u) ? 0xFFFF000000000000ull : 0ull);
              cov[k] |= rep & mk;
            }
          }
        }
      }
    }
    // barrier-free wave compaction (arbitrary order is fine)
    unsigned long long m = __ballot(keep);
    int cw = __popcll(m);
    unsigned int wbase = 0u;
    if (lane == 0 && cw > 0) wbase = atomicAdd(&s_cur, (unsigned int)cw);
    wbase = __shfl(wbase, 0);
    if (keep) {
      unsigned int pos = wbase + (unsigned int)__popcll(m & ((1ull << lane) - 1ull));
      if (pos < CAP) s_ent[pos] = e;
      else bin[pos] = e;                   // overflow: goes straight to global
    }
  }
  // coverage reduce (registers -> per-wave -> tile mask)
#pragma unroll
  for (int off = 1; off < 64; off <<= 1) {
#pragma unroll
    for (int k = 0; k < 4; ++k) cov[k] |= __shfl_xor(cov[k], off);
  }
  if (lane == 0) {
#pragma unroll
    for (int k = 0; k < 4; ++k) s_wcov[wid][k] = cov[k];
  }
  __syncthreads();                          // s_cur/s_hist/s_ent/s_wcov final
  unsigned int cnt = s_cur;
  if (tid < 16) {
    int r = tid, k = r >> 2, sh = (r & 3) * 16;
    unsigned int v = 0u;
#pragma unroll
    for (int w = 0; w < 8; ++w)
      v |= (unsigned int)((s_wcov[w][k] >> sh) & 0xFFFFull);
    covmask[(size_t)(n * NTILE + t) * 16 + r] = v;
  }
  bool sorted = (cnt <= CAP);
  if (sorted) {
    // exclusive scan of 1024-bucket hist: threads 0..255 own 4 buckets each
    unsigned int v0 = 0, v1 = 0, v2 = 0, v3 = 0, sum = 0;
    if (tid < 256) {
      v0 = s_hist[4 * tid]; v1 = s_hist[4 * tid + 1];
      v2 = s_hist[4 * tid + 2]; v3 = s_hist[4 * tid + 3];
      sum = v0 + v1 + v2 + v3;
      s_scan[tid] = sum;
    }
    __syncthreads();
    for (int off = 1; off < 256; off <<= 1) {
      unsigned int x = 0;
      if (tid < 256 && tid >= off) x = s_scan[tid - off];
      __syncthreads();
      if (tid < 256) s_scan[tid] += x;
      __syncthreads();
    }
    if (tid < 256) {
      unsigned int excl = s_scan[tid] - sum;
      s_hist[4 * tid] = excl;
      s_hist[4 * tid + 1] = excl + v0;
      s_hist[4 * tid + 2] = excl + v0 + v1;
      s_hist[4 * tid + 3] = excl + v0 + v1 + v2;
    }
    __syncthreads();
    for (int i = tid; i < (int)cnt; i += 512) {
      unsigned int e = s_ent[i];
      unsigned int pos = atomicAdd(&s_hist[e >> 16], 1u);
      bin[pos] = e;                         // within-bucket order arbitrary: OK,
    }                                       // u64-min result is order-independent
  } else {
    for (int i = tid; i < CAP; i += 512) bin[i] = s_ent[i];
  }
  if (tid < 64) bin[cnt + (unsigned int)tid] = SENTU;   // sentinel pad
  if (tid == 0)
    cursors[n * NTILE + t] = cnt | (sorted ? 0x80000000u : 0u);
}

// Epilogue: interpolate colors for the winning face, apply any-positive mask,
// write NCHW. Recomputes weights via make_rec -> bit-identical values.
__device__ __forceinline__ void emit_pixel(float* __restrict__ out,
    const float* __restrict__ vb, const float* __restrict__ colors,
    const int* __restrict__ faces, int n, int V, int C, int bestf,
    float cx, float cy, int row, int col) {
#pragma clang fp contract(off)
  float cv[8];
#pragma unroll
  for (int ch = 0; ch < 8; ++ch) cv[ch] = 0.0f;
  if (bestf >= 0) {
    int i0 = faces[bestf * 3 + 0], i1 = faces[bestf * 3 + 1], i2 = faces[bestf * 3 + 2];
    FaceRec r = make_rec(vb, faces, bestf);
    float bx = cx - r.x2, by = cy - r.y2;
    float w0 = (r.a0 * bx + r.b0 * by) * r.inv;
    float w1 = (r.a1 * bx + r.b1 * by) * r.inv;
    float w2 = 1.0f - w0 - w1;
    const float* c0 = colors + ((size_t)n * V + i0) * C;
    const float* c1 = colors + ((size_t)n * V + i1) * C;
    const float* c2 = colors + ((size_t)n * V + i2) * C;
    for (int ch = 0; ch < C && ch < 8; ++ch)
      cv[ch] = (w0 * c0[ch] + w1 * c1[ch]) + w2 * c2[ch];
  }
  bool anyp = false;
  for (int ch = 0; ch < C && ch < 8; ++ch) anyp = anyp || (cv[ch] > 0.0f);
  float m = anyp ? 1.0f : 0.0f;
  size_t base = (size_t)n * C * HPIX * WPIX + (size_t)row * WPIX + col;
  for (int ch = 0; ch < C && ch < 8; ++ch)
    out[base + (size_t)ch * HPIX * WPIX] = cv[ch] * m;
}

#define TESTJ(Ak, Bk, Zk, jk)                                                 \
  {                                                                           \
    float bx = cx - Ak.x, by = cy - Ak.y;                                     \
    float w0 = (Ak.z * bx + Ak.w * by) * Bk.z;                                \
    float w1 = (Bk.x * bx + Bk.y * by) * Bk.z;                                \
    float w2 = 1.0f - w0 - w1;                                                \
    float depth = (w0 * Bk.w + w1 * Zk.x) + w2 * Zk.y;                        \
    bool ok = (w0 >= 0.0f) && (w1 >= 0.0f) && (w2 >= 0.0f) && (depth > 0.0f); \
    if (ok) {                                                                 \
      unsigned long long p =                                                  \
          ((unsigned long long)__float_as_uint(depth) << 32) | (unsigned)(jk);\
      if (p < best) best = p;                                                 \
    }                                                                         \
  }

// 16 waves per 8x8 quadrant (round-16 lesson: the dispatch wall is straggler
// waves -- quadrants with a bbox-covered-but-empty pixel whose dcut never
// converges scan their whole bin share serially; doubling segmentation
// halves that serial length while total visits stay constant). Wave w scans
// batches {4w, 4w+64, ...}. Break when all covered lanes' shared depth cut
// beats the batch's bucket lower edge. Per-entry gate: lane needs the test
// only if pixel in bbox AND entry lb <= dcut+EPSB; gate D and A/B/Z share
// one 64B record line.
__global__ __launch_bounds__(1024) void raster_sorted(
    const float4* __restrict__ recs_g, const unsigned int* __restrict__ bins,
    const unsigned int* __restrict__ cursors,
    const unsigned int* __restrict__ covmask,
    const float* __restrict__ verts, const float* __restrict__ colors,
    const int* __restrict__ faces, float* __restrict__ out,
    int V, int F, int FP, int C) {
#pragma clang fp contract(off)
  __shared__ unsigned long long sdmin[64];
  const int bq = blockIdx.x;
  const int t = bq >> 2, quad = bq & 3;
  const int n = blockIdx.y;
  const int tlx = t & 15, tly = t >> 4;
  const int tid = (int)threadIdx.x;
  const int wave = tid >> 6, lane = tid & 63;
  const int tx = lane & 7, ty = lane >> 3;
  const int cloc = (quad & 1) * 8 + tx, rloc = (quad >> 1) * 8 + ty;
  const int col = tlx * TSX + cloc, row = tly * TSY + rloc;
  const float cx = (float)col, cy = (float)row;
  const float4* rb = recs_g + (size_t)n * F * 4;
  const unsigned int* bin = bins + (size_t)(n * NTILE + t) * FP;
  const unsigned int cw = cursors[n * NTILE + t];
  const int cnt = (int)(cw & 0x7FFFFFFFu);
  const bool sorted = (cw & 0x80000000u) != 0u;
  const bool covered =
      (covmask[(size_t)(n * NTILE + t) * 16 + rloc] >> cloc) & 1u;
  if (tid < 64) sdmin[tid] = INIT_PACK;
  __syncthreads();
  unsigned long long best = INIT_PACK;
  if (covered) {
    unsigned long long written = INIT_PACK;
    const int stride = RSEG * 4;
    uint4 E = make_uint4(SENTU, SENTU, SENTU, SENTU);
    int i0 = wave * 4;
    if (i0 < cnt) E = *(const uint4*)(bin + i0);
    for (; i0 < cnt; i0 += stride) {
      int ni = i0 + stride;
      uint4 NE = make_uint4(SENTU, SENTU, SENTU, SENTU);
      if (ni < cnt) NE = *(const uint4*)(bin + ni);
      unsigned long long sh = sdmin[lane];
      float dcut = __uint_as_float((unsigned int)(sh >> 32));  // NaN if INIT
      unsigned int b0 = E.x >> 16;
      float lower0 = (b0 == 0u) ? -3.0e38f
                                : 1.0f + (float)b0 * (1.0f / (float)NB2);
      if (sorted && __all(lower0 > dcut + EPSB)) break;
#define PROCE(ek)                                                             \
      if (ek != SENTU) {                                                      \
        int j = (int)(ek & 0xFFFFu);                                          \
        unsigned int bk = ek >> 16;                                           \
        float lw = (bk == 0u) ? -3.0e38f                                      \
                              : 1.0f + (float)bk * (1.0f / (float)NB2);       \
        float4 D = rb[j * 4 + 3];                                             \
        bool live = (cx >= D.x) && (cx <= D.z) && (cy >= D.y) && (cy <= D.w)  \
                    && !(lw > dcut + EPSB);                                   \
        if (__any(live)) {                                                    \
          float4 A = rb[j * 4 + 0];                                           \
          float4 B = rb[j * 4 + 1];                                           \
          float4 Z = rb[j * 4 + 2];                                           \
          TESTJ(A, B, Z, j);                                                  \
        }                                                                     \
      }
      PROCE(E.x) PROCE(E.y) PROCE(E.z) PROCE(E.w)
#undef PROCE
      if (best < written) { atomicMin(&sdmin[lane], best); written = best; }
      E = NE;
    }
    if (best < written) atomicMin(&sdmin[lane], best);
  }
  __syncthreads();
  if (tid < 64) {
    unsigned long long b = sdmin[lane];
    int bestf = (b == INIT_PACK) ? -1 : (int)(unsigned int)(b & 0xFFFFFFFFull);
    emit_pixel(out, verts + (size_t)n * V * 3, colors, faces, n, V, C, bestf,
               cx, cy, row, col);
  }
}

// ---------- fallbacks (smaller ws or F >= 65536) ----------
__global__ void prep_kernel(const float* __restrict__ verts,
                            const int* __restrict__ faces,
                            float4* __restrict__ recs, int V, int F, int NIMG) {
  int idx = blockIdx.x * blockDim.x + threadIdx.x;
  int total = NIMG * F;
  if (idx >= total) return;
  int n = idx / F, f = idx - n * F;
  FaceRec r = make_rec(verts + (size_t)n * V * 3, faces, f);
  float4* o = recs + (size_t)idx * 4;
  o[0] = make_float4(r.x2, r.y2, r.a0, r.b0);
  o[1] = make_float4(r.a1, r.b1, r.inv, r.z0);
  o[2] = make_float4(r.z1, r.z2, 0.0f, 0.0f);
  o[3] = make_float4(r.xmin, r.ymin, r.xmax, r.ymax);
}

__global__ void init_kernel(unsigned long long* __restrict__ packed, int npix) {
  int i = blockIdx.x * blockDim.x + threadIdx.x;
  if (i < npix) packed[i] = INIT_PACK;
}

__device__ __forceinline__ void test_face(float4 A, float4 B, float4 Z, int f,
                                          float cx, float cy,
                                          unsigned long long& best) {
#pragma clang fp contract(off)
  float bx = cx - A.x, by = cy - A.y;
  float w0 = (A.z * bx + A.w * by) * B.z;
  float w1 = (B.x * bx + B.y * by) * B.z;
  float w2 = 1.0f - w0 - w1;
  float depth = (w0 * B.w + w1 * Z.x) + w2 * Z.y;
  bool ok = (w0 >= 0.0f) && (w1 >= 0.0f) && (w2 >= 0.0f) && (depth > 0.0f);
  if (ok) {
    unsigned long long p =
        ((unsigned long long)__float_as_uint(depth) << 32) | (unsigned int)f;
    best = p < best ? p : best;
  }
}

__global__ __launch_bounds__(256) void raster_seg(
    const float4* __restrict__ recs, unsigned long long* __restrict__ packed,
    int F) {
  const int tx = threadIdx.x, ty = threadIdx.y;
  const int n = blockIdx.z / SEG_FLAT, s = blockIdx.z % SEG_FLAT;
  const int col = blockIdx.x * TSX + tx, row = blockIdx.y * TSY + ty;
  const float cx = (float)col, cy = (float)row;
  const float tX0 = (float)(blockIdx.x * TSX), tX1 = tX0 + (float)(TSX - 1);
  const float tY0 = (float)(blockIdx.y * TSY), tY1 = tY0 + (float)(TSY - 1);
  const float4* rb = recs + (size_t)n * F * 4;
  unsigned long long best = INIT_PACK;
  for (int f = s; f < F; f += SEG_FLAT) {
    float4 bb = rb[f * 4 + 3];
    if (bb.x > tX1 || bb.z < tX0 || bb.y > tY1 || bb.w < tY0) continue;
    float4 A = rb[f * 4 + 0];
    float4 B = rb[f * 4 + 1];
    float4 Z = rb[f * 4 + 2];
    test_face(A, B, Z, f, cx, cy, best);
  }
  if (best != INIT_PACK)
    atomicMin(&packed[(size_t)n * (HPIX * WPIX) + row * WPIX + col], best);
}

__global__ __launch_bounds__(256) void resolve_kernel(
    const unsigned long long* __restrict__ packed,
    const float* __restrict__ verts, const float* __restrict__ colors,
    const int* __restrict__ faces, float* __restrict__ out,
    int V, int F, int C, int NIMG) {
  int i = blockIdx.x * blockDim.x + threadIdx.x;
  int total = NIMG * HPIX * WPIX;
  if (i >= total) return;
  int n = i / (HPIX * WPIX);
  int pix = i - n * (HPIX * WPIX);
  int row = pix >> 8, col = pix & 255;
  unsigned long long p = packed[i];
  int bestf = (p == INIT_PACK) ? -1 : (int)(unsigned int)(p & 0xFFFFFFFFull);
  emit_pixel(out, verts + (size_t)n * V * 3, colors, faces, n, V, C, bestf,
             (float)col, (float)row, row, col);
}

__global__ __launch_bounds__(256) void raster_l(const float* __restrict__ verts,
    const float* __restrict__ colors, const int* __restrict__ faces,
    float* __restrict__ out, int V, int F, int C) {
#pragma clang fp contract(off)
  __shared__ float4 sA[FCH], sB[FCH], sZ[FCH], sD[FCH];
  const int n = blockIdx.z;
  const int tx = threadIdx.x, ty = threadIdx.y;
  const int tid = ty * TSX + tx;
  const int col = blockIdx.x * TSX + tx;
  const int row = blockIdx.y * TSY + ty;
  const float cx = (float)col, cy = (float)row;
  const float tX0 = (float)(blockIdx.x * TSX), tX1 = tX0 + (float)(TSX - 1);
  const float tY0 = (float)(blockIdx.y * TSY), tY1 = tY0 + (float)(TSY - 1);
  const float* vb = verts + (size_t)n * V * 3;
  float bestd = BIGF;
  int bestf = -1;
  for (int base = 0; base < F; base += FCH) {
    int cnt = min(FCH, F - base);
    if (tid < cnt) {
      FaceRec r = make_rec(vb, faces, base + tid);
      sA[tid] = make_float4(r.x2, r.y2, r.a0, r.b0);
      sB[tid] = make_float4(r.a1, r.b1, r.inv, r.z0);
      sZ[tid] = make_float4(r.z1, r.z2, 0.0f, 0.0f);
      sD[tid] = make_float4(r.xmin, r.ymin, r.xmax, r.ymax);
    }
    __syncthreads();
    for (int j = 0; j < cnt; ++j) {
      float4 bb = sD[j];
      if (bb.x > tX1 || bb.z < tX0 || bb.y > tY1 || bb.w < tY0) continue;
      float4 A = sA[j];
      float4 B = sB[j];
      float4 Z = sZ[j];
      float bx = cx - A.x, by = cy - A.y;
      float w0 = (A.z * bx + A.w * by) * B.z;
      float w1 = (B.x * bx + B.y * by) * B.z;
      float w2 = 1.0f - w0 - w1;
      float depth = (w0 * B.w + w1 * Z.x) + w2 * Z.y;
      bool ok = (w0 >= 0.0f) && (w1 >= 0.0f) && (w2 >= 0.0f) && (depth > 0.0f);
      float d = ok ? depth : BIGF;
      if (d < bestd) { bestd = d; bestf = base + j; }
    }
    __syncthreads();
  }
  emit_pixel(out, vb, colors, faces, n, V, C, bestf, cx, cy, row, col);
}

extern "C" void kernel_launch(void* const* d_in, const int* in_sizes, int n_in,
                              void* d_out, int out_size, void* d_ws, size_t ws_size,
                              hipStream_t stream) {
  const float* verts = (const float*)d_in[0];
  const float* colors = (const float*)d_in[1];
  const int* faces = (const int*)d_in[2];
  float* out = (float*)d_out;
  long long s0 = in_sizes[0], s1 = in_sizes[1], s2 = in_sizes[2];
  int C = (int)((3LL * s1) / s0);
  if (C < 1) C = 1;
  int NC = out_size / (HPIX * WPIX);
  int N = NC / C;
  if (N < 1) N = 1;
  int V = (int)(s0 / (3LL * N));
  int F = (int)(s2 / 3);
  int FP = (F + 64 + 3) & ~3;              // bin stride: cnt+64 sentinels, 16B aligned

  // sorted-path ws layout: recs | dq | cursors | covmask | bins
  size_t offR = 0;
  size_t szR4 = (size_t)N * F * 4 * sizeof(float4);
  size_t offD = (offR + szR4 + 255) & ~(size_t)255;
  size_t szD = (size_t)N * F * sizeof(float4);
  size_t offC2 = (offD + szD + 255) & ~(size_t)255;
  size_t szC2 = (size_t)N * NTILE * sizeof(unsigned int);
  size_t offCV = (offC2 + szC2 + 255) & ~(size_t)255;
  size_t szCV = (size_t)N * NTILE * 16 * sizeof(unsigned int);
  size_t offB2 = (offCV + szCV + 255) & ~(size_t)255;
  size_t szB2 = (size_t)N * NTILE * (size_t)FP * sizeof(unsigned int);
  size_t need_sorted = offB2 + szB2;

  // fallback layout: recs | packed
  size_t szR = (size_t)N * F * 4 * sizeof(float4);
  size_t offP = (szR + 255) & ~(size_t)255;
  size_t szP = (size_t)N * HPIX * WPIX * sizeof(unsigned long long);

  dim3 block(TSX, TSY);
  char* ws = (char*)d_ws;
  int total = N * F;
  int npix = N * HPIX * WPIX;

  if (d_ws != nullptr && ws_size >= need_sorted && F < 65536) {
    float4* recs = (float4*)(ws + offR);
    float4* dq = (float4*)(ws + offD);
    unsigned int* cursors = (unsigned int*)(ws + offC2);
    unsigned int* covmask = (unsigned int*)(ws + offCV);
    unsigned int* bins = (unsigned int*)(ws + offB2);
    prep_both<<<(total + 255) / 256, 256, 0, stream>>>(verts, faces, recs, dq,
                                                       V, F, N);
    bin_sort_kernel<<<dim3(NTILE, N), 512, 0, stream>>>(recs, dq, cursors, bins,
                                                        covmask, F, FP);
    raster_sorted<<<dim3(NTILE * 4, N), 1024, 0, stream>>>(recs, bins, cursors,
                                                           covmask, verts, colors,
                                                           faces, out, V, F, FP, C);
  } else if (d_ws != nullptr && ws_size >= offP + szP) {
    float4* recs = (float4*)ws;
    unsigned long long* packed = (unsigned long long*)(ws + offP);
    init_kernel<<<(npix + 255) / 256, 256, 0, stream>>>(packed, npix);
    prep_kernel<<<(total + 255) / 256, 256, 0, stream>>>(verts, faces, recs, V, F, N);
    raster_seg<<<dim3(16, 16, N * SEG_FLAT), block, 0, stream>>>(recs, packed, F);
    resolve_kernel<<<(npix + 255) / 256, 256, 0, stream>>>(packed, verts, colors,
                                                           faces, out, V, F, C, N);
  } else {
    raster_l<<<dim3(16, 16, N), block, 0, stream>>>(verts, colors, faces, out,
                                                    V, F, C);
  }
}

// Round 18
// 112.816 us; speedup vs baseline: 1.0609x; 1.0609x over previous
//
#include <hip/hip_runtime.h>

#define HPIX 256
#define WPIX 256
#define TSX 16
#define TSY 16
#define NTILE 256            // 16x16 tiles of 16x16 px
#define FCH 256
#define SEG_FLAT 16          // segments over all faces (fallback path)
#define RSEG 8               // waves (bin segments) per quadrant block
#define CAP 6144             // LDS sort capacity (entries per tile bin)
#define NB2 1024             // per-tile depth-lb buckets
#define SENTU 0xFFFFFFFFu
#define BIGF 1000000000.0f
#define EPSF 1e-8f
#define MARGIN 0.125f
#define HP_SLOP 0.0625f      // >= 4x the FP eval error bound (~0.015 w-units)
#define EPSB 2.5e-4f         // break/prune slop: 2.5x the lb FP error (<1e-4)
#define WBOUND 64.0f         // corner-|w| bound for tight corner-lb FP error
#define INIT_PACK 0xFFFFFFFFFFFFFFFFull

struct FaceRec {
  float x2, y2, a0, b0, a1, b1, inv, z0, z1, z2;
  float xmin, ymin, xmax, ymax;
};

// Compute the per-face record with EXACTLY the reference's op order (no FMA).
__device__ __forceinline__ FaceRec make_rec(const float* __restrict__ vb,
                                            const int* __restrict__ faces, int f) {
#pragma clang fp contract(off)
  FaceRec r;
  int i0 = faces[f * 3 + 0], i1 = faces[f * 3 + 1], i2 = faces[f * 3 + 2];
  float x0 = vb[i0 * 3 + 0], y0 = vb[i0 * 3 + 1], z0 = vb[i0 * 3 + 2];
  float x1 = vb[i1 * 3 + 0], y1 = vb[i1 * 3 + 1], z1 = vb[i1 * 3 + 2];
  float x2 = vb[i2 * 3 + 0], y2 = vb[i2 * 3 + 1], z2 = vb[i2 * 3 + 2];
  float px0 = x0 / z0, py0 = y0 / z0;
  float px1 = x1 / z1, py1 = y1 / z1;
  float px2 = x2 / z2, py2 = y2 / z2;
  float a0 = py1 - py2, b0 = px2 - px1;   // (y1-y2), (x2-x1)
  float a1 = py2 - py0, b1 = px0 - px2;   // (y2-y0), (x0-x2)
  float dy02 = py0 - py2;
  float denom = a0 * b1 + b0 * dy02;      // (y1-y2)*(x0-x2) + (x2-x1)*(y0-y2)
  bool nz = fabsf(denom) > EPSF;
  bool valid = nz && (z0 > 0.0f) && (z1 > 0.0f) && (z2 > 0.0f);
  r.x2 = px2; r.y2 = py2; r.a0 = a0; r.b0 = b0; r.a1 = a1; r.b1 = b1;
  r.inv = valid ? 1.0f / denom : 0.0f;
  r.z0 = z0; r.z1 = z1;
  r.z2 = valid ? z2 : -1.0f;              // invalid -> depth<0 -> fails depth>0
  if (valid) {
    r.xmin = fminf(px0, fminf(px1, px2)) - MARGIN;
    r.xmax = fmaxf(px0, fmaxf(px1, px2)) + MARGIN;
    r.ymin = fminf(py0, fminf(py1, py2)) - MARGIN;
    r.ymax = fmaxf(py0, fmaxf(py1, py2)) + MARGIN;
  } else {
    r.xmin = 2.0f * BIGF; r.xmax = -2.0f * BIGF;
    r.ymin = 2.0f * BIGF; r.ymax = -2.0f * BIGF;
  }
  return r;
}

// prep (dual layout): 64B-aligned combined record (random access: one cache
// line covers A+B+Z+D) AND dense 16B bbox array (streaming sieve).
__global__ void prep_both(const float* __restrict__ verts,
                          const int* __restrict__ faces,
                          float4* __restrict__ recs, float4* __restrict__ dq,
                          int V, int F, int NIMG) {
  int idx = blockIdx.x * blockDim.x + threadIdx.x;
  if (idx >= NIMG * F) return;
  int n = idx / F, f = idx - n * F;
  FaceRec r = make_rec(verts + (size_t)n * V * 3, faces, f);
  float4* o = recs + (size_t)idx * 4;
  float4 D = make_float4(r.xmin, r.ymin, r.xmax, r.ymax);
  o[0] = make_float4(r.x2, r.y2, r.a0, r.b0);
  o[1] = make_float4(r.a1, r.b1, r.inv, r.z0);
  o[2] = make_float4(r.z1, r.z2, 0.0f, 0.0f);
  o[3] = D;
  dq[idx] = D;
}

// Per (tile,image), 512 threads: stream faces (dense bbox sieve via dq),
// keep = bbox overlap + conservative corner half-plane. Sort key:
// lb = max(corner-min depth, minz - margin). Barrier-free face loop
// (round-14: entry order irrelevant, counting sort reorders anyway).
__global__ __launch_bounds__(512) void bin_sort_kernel(
    const float4* __restrict__ recs_g, const float4* __restrict__ dq_g,
    unsigned int* __restrict__ cursors, unsigned int* __restrict__ bins,
    unsigned int* __restrict__ covmask, int F, int FP) {
#pragma clang fp contract(off)
  const int t = blockIdx.x, n = blockIdx.y;
  const int tlx = t & 15, tly = t >> 4;
  const float X0 = (float)(tlx * TSX), X1 = X0 + (float)(TSX - 1);
  const float Y0 = (float)(tly * TSY), Y1 = Y0 + (float)(TSY - 1);
  __shared__ unsigned int s_ent[CAP];
  __shared__ unsigned int s_hist[NB2];
  __shared__ unsigned int s_scan[256];
  __shared__ unsigned int s_cur;
  __shared__ unsigned long long s_wcov[8][4];
  const int tid = (int)threadIdx.x;
  const int lane = tid & 63, wid = tid >> 6;
  if (tid == 0) s_cur = 0u;
  for (int i = tid; i < NB2; i += 512) s_hist[i] = 0u;
  __syncthreads();
  const float4* rb = recs_g + (size_t)n * F * 4;
  const float4* dq = dq_g + (size_t)n * F;
  unsigned int* bin = bins + (size_t)(n * NTILE + t) * FP;
  unsigned long long cov[4] = {0ull, 0ull, 0ull, 0ull};
  for (int j = tid; j < F; j += 512) {
    bool keep = false;
    unsigned int e = 0u;
    {
      float4 D = dq[j];
      keep = (D.x <= X1) && (D.z >= X0) && (D.y <= Y1) && (D.w >= Y0);
      if (keep) {
        float4 A = rb[j * 4 + 0];
        float4 B = rb[j * 4 + 1];
        float4 Z = rb[j * 4 + 2];
        float inv = B.z;
        // minz lower bound: valid for any passing pixel (w>=0, sum=1+-2.4e-7
        // => depth >= minz - 1.2e-6; margin 2e-5 >> error).
        float minz3 = fminf(B.w, fminf(Z.x, Z.y));
        float lb = minz3 - (1e-5f + 1e-5f * fabsf(minz3));
        if (fabsf(inv) <= 1.0f) {
          float m0 = -3.0e38f, m1 = -3.0e38f, m2 = -3.0e38f;
          float g = 0.0f, dmin = 3.0e38f;
#pragma unroll
          for (int c = 0; c < 4; ++c) {
            float ccx = (c & 1) ? X1 : X0;
            float ccy = (c & 2) ? Y1 : Y0;
            float bx = ccx - A.x, by = ccy - A.y;
            float w0 = (A.z * bx + A.w * by) * inv;
            float w1 = (B.x * bx + B.y * by) * inv;
            float w2 = 1.0f - w0 - w1;
            float dc = (w0 * B.w + w1 * Z.x) + w2 * Z.y;
            m0 = fmaxf(m0, w0); m1 = fmaxf(m1, w1); m2 = fmaxf(m2, w2);
            g = fmaxf(g, fmaxf(fabsf(w0), fmaxf(fabsf(w1), fabsf(w2))));
            dmin = fminf(dmin, dc);
          }
          keep = (m0 >= -HP_SLOP) && (m1 >= -HP_SLOP) && (m2 >= -HP_SLOP);
          if (g <= WBOUND) lb = fmaxf(lb, dmin);   // tighter of the two bounds
        }
        if (keep) {
          int bq = (lb <= 1.0f) ? 0 : (int)floorf((lb - 1.0f) * (float)NB2);
          bq = bq < 0 ? 0 : (bq > NB2 - 1 ? NB2 - 1 : bq);
          e = ((unsigned int)bq << 16) | (unsigned int)j;
          atomicAdd(&s_hist[bq], 1u);
          // coverage rectangle into registers (no LDS atomics -- r9 lesson)
          int cmin = (int)ceilf(D.x - X0);  cmin = cmin < 0 ? 0 : cmin;
          int cmax = (int)floorf(D.z - X0); cmax = cmax > 15 ? 15 : cmax;
          int rmin = (int)ceilf(D.y - Y0);  rmin = rmin < 0 ? 0 : rmin;
          int rmax = (int)floorf(D.w - Y0); rmax = rmax > 15 ? 15 : rmax;
          if (cmin <= cmax && rmin <= rmax) {
            unsigned int colm = (0xFFFFu << cmin) & (0xFFFFu >> (15 - cmax));
            unsigned int rowm = (0xFFFFu << rmin) & (0xFFFFu >> (15 - rmax));
            unsigned long long rep =
                (unsigned long long)colm * 0x0001000100010001ull;
#pragma unroll
            for (int k = 0; k < 4; ++k) {
              unsigned int rm4 = (rowm >> (4 * k)) & 0xFu;
              unsigned long long mk =
                  ((rm4 & 1u) ? 0x000000000000FFFFull : 0ull) |
                  ((rm4 & 2u) ? 0x00000000FFFF0000ull : 0ull) |
                  ((rm4 & 4u) ? 0x0000FFFF00000000ull : 0ull) |
                  ((rm4 & 8u) ? 0xFFFF000000000000ull : 0ull);
              cov[k] |= rep & mk;
            }
          }
        }
      }
    }
    // barrier-free wave compaction (arbitrary order is fine)
    unsigned long long m = __ballot(keep);
    int cw = __popcll(m);
    unsigned int wbase = 0u;
    if (lane == 0 && cw > 0) wbase = atomicAdd(&s_cur, (unsigned int)cw);
    wbase = __shfl(wbase, 0);
    if (keep) {
      unsigned int pos = wbase + (unsigned int)__popcll(m & ((1ull << lane) - 1ull));
      if (pos < CAP) s_ent[pos] = e;
      else bin[pos] = e;                   // overflow: goes straight to global
    }
  }
  // coverage reduce (registers -> per-wave -> tile mask)
#pragma unroll
  for (int off = 1; off < 64; off <<= 1) {
#pragma unroll
    for (int k = 0; k < 4; ++k) cov[k] |= __shfl_xor(cov[k], off);
  }
  if (lane == 0) {
#pragma unroll
    for (int k = 0; k < 4; ++k) s_wcov[wid][k] = cov[k];
  }
  __syncthreads();                          // s_cur/s_hist/s_ent/s_wcov final
  unsigned int cnt = s_cur;
  if (tid < 16) {
    int r = tid, k = r >> 2, sh = (r & 3) * 16;
    unsigned int v = 0u;
#pragma unroll
    for (int w = 0; w < 8; ++w)
      v |= (unsigned int)((s_wcov[w][k] >> sh) & 0xFFFFull);
    covmask[(size_t)(n * NTILE + t) * 16 + r] = v;
  }
  bool sorted = (cnt <= CAP);
  if (sorted) {
    // exclusive scan of 1024-bucket hist: threads 0..255 own 4 buckets each
    unsigned int v0 = 0, v1 = 0, v2 = 0, v3 = 0, sum = 0;
    if (tid < 256) {
      v0 = s_hist[4 * tid]; v1 = s_hist[4 * tid + 1];
      v2 = s_hist[4 * tid + 2]; v3 = s_hist[4 * tid + 3];
      sum = v0 + v1 + v2 + v3;
      s_scan[tid] = sum;
    }
    __syncthreads();
    for (int off = 1; off < 256; off <<= 1) {
      unsigned int x = 0;
      if (tid < 256 && tid >= off) x = s_scan[tid - off];
      __syncthreads();
      if (tid < 256) s_scan[tid] += x;
      __syncthreads();
    }
    if (tid < 256) {
      unsigned int excl = s_scan[tid] - sum;
      s_hist[4 * tid] = excl;
      s_hist[4 * tid + 1] = excl + v0;
      s_hist[4 * tid + 2] = excl + v0 + v1;
      s_hist[4 * tid + 3] = excl + v0 + v1 + v2;
    }
    __syncthreads();
    for (int i = tid; i < (int)cnt; i += 512) {
      unsigned int e = s_ent[i];
      unsigned int pos = atomicAdd(&s_hist[e >> 16], 1u);
      bin[pos] = e;                         // within-bucket order arbitrary: OK,
    }                                       // u64-min result is order-independent
  } else {
    for (int i = tid; i < CAP; i += 512) bin[i] = s_ent[i];
  }
  if (tid < 64) bin[cnt + (unsigned int)tid] = SENTU;   // sentinel pad
  if (tid == 0)
    cursors[n * NTILE + t] = cnt | (sorted ? 0x80000000u : 0u);
}

// Epilogue: interpolate colors for the winning face, apply any-positive mask,
// write NCHW. Recomputes weights via make_rec -> bit-identical values.
__device__ __forceinline__ void emit_pixel(float* __restrict__ out,
    const float* __restrict__ vb, const float* __restrict__ colors,
    const int* __restrict__ faces, int n, int V, int C, int bestf,
    float cx, float cy, int row, int col) {
#pragma clang fp contract(off)
  float cv[8];
#pragma unroll
  for (int ch = 0; ch < 8; ++ch) cv[ch] = 0.0f;
  if (bestf >= 0) {
    int i0 = faces[bestf * 3 + 0], i1 = faces[bestf * 3 + 1], i2 = faces[bestf * 3 + 2];
    FaceRec r = make_rec(vb, faces, bestf);
    float bx = cx - r.x2, by = cy - r.y2;
    float w0 = (r.a0 * bx + r.b0 * by) * r.inv;
    float w1 = (r.a1 * bx + r.b1 * by) * r.inv;
    float w2 = 1.0f - w0 - w1;
    const float* c0 = colors + ((size_t)n * V + i0) * C;
    const float* c1 = colors + ((size_t)n * V + i1) * C;
    const float* c2 = colors + ((size_t)n * V + i2) * C;
    for (int ch = 0; ch < C && ch < 8; ++ch)
      cv[ch] = (w0 * c0[ch] + w1 * c1[ch]) + w2 * c2[ch];
  }
  bool anyp = false;
  for (int ch = 0; ch < C && ch < 8; ++ch) anyp = anyp || (cv[ch] > 0.0f);
  float m = anyp ? 1.0f : 0.0f;
  size_t base = (size_t)n * C * HPIX * WPIX + (size_t)row * WPIX + col;
  for (int ch = 0; ch < C && ch < 8; ++ch)
    out[base + (size_t)ch * HPIX * WPIX] = cv[ch] * m;
}

#define TESTJ(Ak, Bk, Zk, jk)                                                 \
  {                                                                           \
    float bx = cx - Ak.x, by = cy - Ak.y;                                     \
    float w0 = (Ak.z * bx + Ak.w * by) * Bk.z;                                \
    float w1 = (Bk.x * bx + Bk.y * by) * Bk.z;                                \
    float w2 = 1.0f - w0 - w1;                                                \
    float depth = (w0 * Bk.w + w1 * Zk.x) + w2 * Zk.y;                        \
    bool ok = (w0 >= 0.0f) && (w1 >= 0.0f) && (w2 >= 0.0f) && (depth > 0.0f); \
    if (ok) {                                                                 \
      unsigned long long p =                                                  \
          ((unsigned long long)__float_as_uint(depth) << 32) | (unsigned)(jk);\
      if (p < best) best = p;                                                 \
    }                                                                         \
  }

// 8 waves per 8x8 quadrant (round-15 configuration -- measured best; 16-wave
// variant regressed: minimum visit floor and sdmin contention double). Wave w
// scans batches {4w, 4w+32, ...} of the lb-sorted bin (bucket-ascending).
// Break when all covered lanes' shared depth cut beats the batch's bucket
// lower edge. Per-entry gate: lane needs the test only if pixel in bbox AND
// entry lb <= dcut+EPSB; gate D and A/B/Z share one 64B record line.
__global__ __launch_bounds__(512) void raster_sorted(
    const float4* __restrict__ recs_g, const unsigned int* __restrict__ bins,
    const unsigned int* __restrict__ cursors,
    const unsigned int* __restrict__ covmask,
    const float* __restrict__ verts, const float* __restrict__ colors,
    const int* __restrict__ faces, float* __restrict__ out,
    int V, int F, int FP, int C) {
#pragma clang fp contract(off)
  __shared__ unsigned long long sdmin[64];
  const int bq = blockIdx.x;
  const int t = bq >> 2, quad = bq & 3;
  const int n = blockIdx.y;
  const int tlx = t & 15, tly = t >> 4;
  const int tid = (int)threadIdx.x;
  const int wave = tid >> 6, lane = tid & 63;
  const int tx = lane & 7, ty = lane >> 3;
  const int cloc = (quad & 1) * 8 + tx, rloc = (quad >> 1) * 8 + ty;
  const int col = tlx * TSX + cloc, row = tly * TSY + rloc;
  const float cx = (float)col, cy = (float)row;
  const float4* rb = recs_g + (size_t)n * F * 4;
  const unsigned int* bin = bins + (size_t)(n * NTILE + t) * FP;
  const unsigned int cw = cursors[n * NTILE + t];
  const int cnt = (int)(cw & 0x7FFFFFFFu);
  const bool sorted = (cw & 0x80000000u) != 0u;
  const bool covered =
      (covmask[(size_t)(n * NTILE + t) * 16 + rloc] >> cloc) & 1u;
  if (tid < 64) sdmin[tid] = INIT_PACK;
  __syncthreads();
  unsigned long long best = INIT_PACK;
  if (covered) {
    unsigned long long written = INIT_PACK;
    const int stride = RSEG * 4;
    uint4 E = make_uint4(SENTU, SENTU, SENTU, SENTU);
    int i0 = wave * 4;
    if (i0 < cnt) E = *(const uint4*)(bin + i0);
    for (; i0 < cnt; i0 += stride) {
      int ni = i0 + stride;
      uint4 NE = make_uint4(SENTU, SENTU, SENTU, SENTU);
      if (ni < cnt) NE = *(const uint4*)(bin + ni);
      unsigned long long sh = sdmin[lane];
      float dcut = __uint_as_float((unsigned int)(sh >> 32));  // NaN if INIT
      unsigned int b0 = E.x >> 16;
      float lower0 = (b0 == 0u) ? -3.0e38f
                                : 1.0f + (float)b0 * (1.0f / (float)NB2);
      if (sorted && __all(lower0 > dcut + EPSB)) break;
#define PROCE(ek)                                                             \
      if (ek != SENTU) {                                                      \
        int j = (int)(ek & 0xFFFFu);                                          \
        unsigned int bk = ek >> 16;                                           \
        float lw = (bk == 0u) ? -3.0e38f                                      \
                              : 1.0f + (float)bk * (1.0f / (float)NB2);       \
        float4 D = rb[j * 4 + 3];                                             \
        bool live = (cx >= D.x) && (cx <= D.z) && (cy >= D.y) && (cy <= D.w)  \
                    && !(lw > dcut + EPSB);                                   \
        if (__any(live)) {                                                    \
          float4 A = rb[j * 4 + 0];                                           \
          float4 B = rb[j * 4 + 1];                                           \
          float4 Z = rb[j * 4 + 2];                                           \
          TESTJ(A, B, Z, j);                                                  \
        }                                                                     \
      }
      PROCE(E.x) PROCE(E.y) PROCE(E.z) PROCE(E.w)
#undef PROCE
      if (best < written) { atomicMin(&sdmin[lane], best); written = best; }
      E = NE;
    }
    if (best < written) atomicMin(&sdmin[lane], best);
  }
  __syncthreads();
  if (tid < 64) {
    unsigned long long b = sdmin[lane];
    int bestf = (b == INIT_PACK) ? -1 : (int)(unsigned int)(b & 0xFFFFFFFFull);
    emit_pixel(out, verts + (size_t)n * V * 3, colors, faces, n, V, C, bestf,
               cx, cy, row, col);
  }
}

// ---------- fallbacks (smaller ws or F >= 65536) ----------
__global__ void prep_kernel(const float* __restrict__ verts,
                            const int* __restrict__ faces,
                            float4* __restrict__ recs, int V, int F, int NIMG) {
  int idx = blockIdx.x * blockDim.x + threadIdx.x;
  int total = NIMG * F;
  if (idx >= total) return;
  int n = idx / F, f = idx - n * F;
  FaceRec r = make_rec(verts + (size_t)n * V * 3, faces, f);
  float4* o = recs + (size_t)idx * 4;
  o[0] = make_float4(r.x2, r.y2, r.a0, r.b0);
  o[1] = make_float4(r.a1, r.b1, r.inv, r.z0);
  o[2] = make_float4(r.z1, r.z2, 0.0f, 0.0f);
  o[3] = make_float4(r.xmin, r.ymin, r.xmax, r.ymax);
}

__global__ void init_kernel(unsigned long long* __restrict__ packed, int npix) {
  int i = blockIdx.x * blockDim.x + threadIdx.x;
  if (i < npix) packed[i] = INIT_PACK;
}

__device__ __forceinline__ void test_face(float4 A, float4 B, float4 Z, int f,
                                          float cx, float cy,
                                          unsigned long long& best) {
#pragma clang fp contract(off)
  float bx = cx - A.x, by = cy - A.y;
  float w0 = (A.z * bx + A.w * by) * B.z;
  float w1 = (B.x * bx + B.y * by) * B.z;
  float w2 = 1.0f - w0 - w1;
  float depth = (w0 * B.w + w1 * Z.x) + w2 * Z.y;
  bool ok = (w0 >= 0.0f) && (w1 >= 0.0f) && (w2 >= 0.0f) && (depth > 0.0f);
  if (ok) {
    unsigned long long p =
        ((unsigned long long)__float_as_uint(depth) << 32) | (unsigned int)f;
    best = p < best ? p : best;
  }
}

__global__ __launch_bounds__(256) void raster_seg(
    const float4* __restrict__ recs, unsigned long long* __restrict__ packed,
    int F) {
  const int tx = threadIdx.x, ty = threadIdx.y;
  const int n = blockIdx.z / SEG_FLAT, s = blockIdx.z % SEG_FLAT;
  const int col = blockIdx.x * TSX + tx, row = blockIdx.y * TSY + ty;
  const float cx = (float)col, cy = (float)row;
  const float tX0 = (float)(blockIdx.x * TSX), tX1 = tX0 + (float)(TSX - 1);
  const float tY0 = (float)(blockIdx.y * TSY), tY1 = tY0 + (float)(TSY - 1);
  const float4* rb = recs + (size_t)n * F * 4;
  unsigned long long best = INIT_PACK;
  for (int f = s; f < F; f += SEG_FLAT) {
    float4 bb = rb[f * 4 + 3];
    if (bb.x > tX1 || bb.z < tX0 || bb.y > tY1 || bb.w < tY0) continue;
    float4 A = rb[f * 4 + 0];
    float4 B = rb[f * 4 + 1];
    float4 Z = rb[f * 4 + 2];
    test_face(A, B, Z, f, cx, cy, best);
  }
  if (best != INIT_PACK)
    atomicMin(&packed[(size_t)n * (HPIX * WPIX) + row * WPIX + col], best);
}

__global__ __launch_bounds__(256) void resolve_kernel(
    const unsigned long long* __restrict__ packed,
    const float* __restrict__ verts, const float* __restrict__ colors,
    const int* __restrict__ faces, float* __restrict__ out,
    int V, int F, int C, int NIMG) {
  int i = blockIdx.x * blockDim.x + threadIdx.x;
  int total = NIMG * HPIX * WPIX;
  if (i >= total) return;
  int n = i / (HPIX * WPIX);
  int pix = i - n * (HPIX * WPIX);
  int row = pix >> 8, col = pix & 255;
  unsigned long long p = packed[i];
  int bestf = (p == INIT_PACK) ? -1 : (int)(unsigned int)(p & 0xFFFFFFFFull);
  emit_pixel(out, verts + (size_t)n * V * 3, colors, faces, n, V, C, bestf,
             (float)col, (float)row, row, col);
}

__global__ __launch_bounds__(256) void raster_l(const float* __restrict__ verts,
    const float* __restrict__ colors, const int* __restrict__ faces,
    float* __restrict__ out, int V, int F, int C) {
#pragma clang fp contract(off)
  __shared__ float4 sA[FCH], sB[FCH], sZ[FCH], sD[FCH];
  const int n = blockIdx.z;
  const int tx = threadIdx.x, ty = threadIdx.y;
  const int tid = ty * TSX + tx;
  const int col = blockIdx.x * TSX + tx;
  const int row = blockIdx.y * TSY + ty;
  const float cx = (float)col, cy = (float)row;
  const float tX0 = (float)(blockIdx.x * TSX), tX1 = tX0 + (float)(TSX - 1);
  const float tY0 = (float)(blockIdx.y * TSY), tY1 = tY0 + (float)(TSY - 1);
  const float* vb = verts + (size_t)n * V * 3;
  float bestd = BIGF;
  int bestf = -1;
  for (int base = 0; base < F; base += FCH) {
    int cnt = min(FCH, F - base);
    if (tid < cnt) {
      FaceRec r = make_rec(vb, faces, base + tid);
      sA[tid] = make_float4(r.x2, r.y2, r.a0, r.b0);
      sB[tid] = make_float4(r.a1, r.b1, r.inv, r.z0);
      sZ[tid] = make_float4(r.z1, r.z2, 0.0f, 0.0f);
      sD[tid] = make_float4(r.xmin, r.ymin, r.xmax, r.ymax);
    }
    __syncthreads();
    for (int j = 0; j < cnt; ++j) {
      float4 bb = sD[j];
      if (bb.x > tX1 || bb.z < tX0 || bb.y > tY1 || bb.w < tY0) continue;
      float4 A = sA[j];
      float4 B = sB[j];
      float4 Z = sZ[j];
      float bx = cx - A.x, by = cy - A.y;
      float w0 = (A.z * bx + A.w * by) * B.z;
      float w1 = (B.x * bx + B.y * by) * B.z;
      float w2 = 1.0f - w0 - w1;
      float depth = (w0 * B.w + w1 * Z.x) + w2 * Z.y;
      bool ok = (w0 >= 0.0f) && (w1 >= 0.0f) && (w2 >= 0.0f) && (depth > 0.0f);
      float d = ok ? depth : BIGF;
      if (d < bestd) { bestd = d; bestf = base + j; }
    }
    __syncthreads();
  }
  emit_pixel(out, vb, colors, faces, n, V, C, bestf, cx, cy, row, col);
}

extern "C" void kernel_launch(void* const* d_in, const int* in_sizes, int n_in,
                              void* d_out, int out_size, void* d_ws, size_t ws_size,
                              hipStream_t stream) {
  const float* verts = (const float*)d_in[0];
  const float* colors = (const float*)d_in[1];
  const int* faces = (const int*)d_in[2];
  float* out = (float*)d_out;
  long long s0 = in_sizes[0], s1 = in_sizes[1], s2 = in_sizes[2];
  int C = (int)((3LL * s1) / s0);
  if (C < 1) C = 1;
  int NC = out_size / (HPIX * WPIX);
  int N = NC / C;
  if (N < 1) N = 1;
  int V = (int)(s0 / (3LL * N));
  int F = (int)(s2 / 3);
  int FP = (F + 64 + 3) & ~3;              // bin stride: cnt+64 sentinels, 16B aligned

  // sorted-path ws layout: recs | dq | cursors | covmask | bins
  size_t offR = 0;
  size_t szR4 = (size_t)N * F * 4 * sizeof(float4);
  size_t offD = (offR + szR4 + 255) & ~(size_t)255;
  size_t szD = (size_t)N * F * sizeof(float4);
  size_t offC2 = (offD + szD + 255) & ~(size_t)255;
  size_t szC2 = (size_t)N * NTILE * sizeof(unsigned int);
  size_t offCV = (offC2 + szC2 + 255) & ~(size_t)255;
  size_t szCV = (size_t)N * NTILE * 16 * sizeof(unsigned int);
  size_t offB2 = (offCV + szCV + 255) & ~(size_t)255;
  size_t szB2 = (size_t)N * NTILE * (size_t)FP * sizeof(unsigned int);
  size_t need_sorted = offB2 + szB2;

  // fallback layout: recs | packed
  size_t szR = (size_t)N * F * 4 * sizeof(float4);
  size_t offP = (szR + 255) & ~(size_t)255;
  size_t szP = (size_t)N * HPIX * WPIX * sizeof(unsigned long long);

  dim3 block(TSX, TSY);
  char* ws = (char*)d_ws;
  int total = N * F;
  int npix = N * HPIX * WPIX;

  if (d_ws != nullptr && ws_size >= need_sorted && F < 65536) {
    float4* recs = (float4*)(ws + offR);
    float4* dq = (float4*)(ws + offD);
    unsigned int* cursors = (unsigned int*)(ws + offC2);
    unsigned int* covmask = (unsigned int*)(ws + offCV);
    unsigned int* bins = (unsigned int*)(ws + offB2);
    prep_both<<<(total + 255) / 256, 256, 0, stream>>>(verts, faces, recs, dq,
                                                       V, F, N);
    bin_sort_kernel<<<dim3(NTILE, N), 512, 0, stream>>>(recs, dq, cursors, bins,
                                                        covmask, F, FP);
    raster_sorted<<<dim3(NTILE * 4, N), 512, 0, stream>>>(recs, bins, cursors,
                                                          covmask, verts, colors,
                                                          faces, out, V, F, FP, C);
  } else if (d_ws != nullptr && ws_size >= offP + szP) {
    float4* recs = (float4*)ws;
    unsigned long long* packed = (unsigned long long*)(ws + offP);
    init_kernel<<<(npix + 255) / 256, 256, 0, stream>>>(packed, npix);
    prep_kernel<<<(total + 255) / 256, 256, 0, stream>>>(verts, faces, recs, V, F, N);
    raster_seg<<<dim3(16, 16, N * SEG_FLAT), block, 0, stream>>>(recs, packed, F);
    resolve_kernel<<<(npix + 255) / 256, 256, 0, stream>>>(packed, verts, colors,
                                                           faces, out, V, F, C, N);
  } else {
    raster_l<<<dim3(16, 16, N), block, 0, stream>>>(verts, colors, faces, out,
                                                    V, F, C);
  }
}